// Round 15
// baseline (2020.381 us; speedup 1.0000x reference)
//
#include <hip/hip_runtime.h>
#include <math.h>

#define NB 8
#define NV 64
#define NM 1024
#define NR 3
#define NT 16
#define KR 8
#define RTOT 48                 // NR*NT
#define RADIUSF 40.0f
#define TWO_PIF 6.283185307179586f

// ---------------------------------------------------------------------------
// bf16 pack/unpack (RNE). Unpack exact. Validated R14 (absmax 2e-3).
// ---------------------------------------------------------------------------
__device__ __forceinline__ unsigned int pack_bf16x2(float a, float b) {
    unsigned int ua = __float_as_uint(a), ub = __float_as_uint(b);
    ua = (ua + 0x7FFFu + ((ua >> 16) & 1u)) >> 16;
    ub = (ub + 0x7FFFu + ((ub >> 16) & 1u)) & 0xFFFF0000u;
    return ua | ub;
}
__device__ __forceinline__ float2 unpack_bf16x2(unsigned int u) {
    float2 r;
    r.x = __uint_as_float(u << 16);
    r.y = __uint_as_float(u & 0xFFFF0000u);
    return r;
}

// ---------------------------------------------------------------------------
// Branchless fast atan2 (validated R12-R14).
// ---------------------------------------------------------------------------
__device__ __forceinline__ float fast_atan2(float y, float x) {
    float ax = fabsf(x), ay = fabsf(y);
    float mx = fmaxf(ax, ay), mn = fminf(ax, ay);
    float z = mn / fmaxf(mx, 1e-30f);
    float z2 = z * z;
    float r = fmaf(z2, fmaf(z2, fmaf(z2, fmaf(z2, 0.0208351f, -0.0851330f),
                                     0.1801410f), -0.3302995f), 0.9998660f) * z;
    r = (ay > ax) ? (1.57079637f - r) : r;
    r = (x < 0.f) ? (3.14159274f - r) : r;
    return (y < 0.f) ? -r : r;
}

// ---------------------------------------------------------------------------
// Pair geometry: reference bilinear polar binning.
// ---------------------------------------------------------------------------
__device__ __forceinline__ void pair_geom(float relx, float rely, float mask,
                                          float& valid, float& win,
                                          int bin[4], float cw[4]) {
    float d = sqrtf(relx * relx + rely * rely + 1e-12f);
    valid = (d < RADIUSF) ? mask : 0.0f;
    float q = d * (1.0f / RADIUSF);
    float w1 = fmaxf(1.0f - q * q, 0.0f);
    win = w1 * w1 * w1;
    float u = fminf(fmaxf(q, 0.0f), 1.0f) * (float)(NR - 1);
    float r0f = floorf(u);
    float wr = u - r0f;
    int r0 = (int)r0f;
    int r1 = min(r0 + 1, NR - 1);
    float a = fast_atan2(rely, relx) * (1.0f / TWO_PIF);
    a = a - floorf(a);                  // mod 1 -> [0,1)
    float t = a * (float)NT;
    float t0f = floorf(t);
    float wt = t - t0f;
    int t0 = ((int)t0f) & (NT - 1);
    int t1 = (t0 + 1) & (NT - 1);
    bin[0] = r0 * NT + t0; cw[0] = (1.0f - wr) * (1.0f - wt);
    bin[1] = r0 * NT + t1; cw[1] = (1.0f - wr) * wt;
    bin[2] = r1 * NT + t0; cw[2] = wr * (1.0f - wt);
    bin[3] = r1 * NT + t1; cw[3] = wr * wt;
}

// ---------------------------------------------------------------------------
// One-time K transpose: KT[chunk j][pair p].
// ---------------------------------------------------------------------------
__global__ __launch_bounds__(256) void k_trans(
        const float* __restrict__ Kv, const float* __restrict__ K1g,
        const float* __restrict__ K2g, float4* __restrict__ KTv,
        float4* __restrict__ KT1, float4* __restrict__ KT2) {
    int idx = blockIdx.x * 256 + threadIdx.x;
    if (idx < 48 * 384) {
        int j = idx / 384, p = idx % 384;
        KTv[idx] = *(const float4*)(Kv + p * 192 + j * 4);
    } else if (idx < 48 * 384 + 16 * 384) {
        int r = idx - 48 * 384;
        int j = r / 384, p = r % 384;
        KT1[r] = *(const float4*)(K1g + p * 64 + j * 4);
    } else if (idx < 48 * 384 + 16 * 384 + 16 * 144) {
        int r = idx - (48 * 384 + 16 * 384);
        int j = r / 144, p = r % 144;
        KT2[r] = *(const float4*)(K2g + p * 64 + j * 4);
    }
}

// ---------------------------------------------------------------------------
// h_phase: circular conv of LDS feature row with KT -> bf16 H rows.
// STRIDE = blockDim.x of the calling kernel.
// ---------------------------------------------------------------------------
template<int ICH, int NPAIR, int OCH, int ROWLEN, int STRIDE>
__device__ __forceinline__ void h_phase(int tid, int bn, const float* s_f,
        const float4* __restrict__ KT, unsigned short* __restrict__ Hb) {
    for (int pp = tid; pp < NPAIR; pp += STRIDE) {
        float acc[KR];
#pragma unroll
        for (int m = 0; m < KR; ++m) acc[m] = 0.f;
#pragma unroll 8
        for (int i = 0; i < ICH; ++i) {
            float4 k0 = KT[(2 * i) * NPAIR + pp];
            float4 k1 = KT[(2 * i + 1) * NPAIR + pp];
            float kk[8] = {k0.x, k0.y, k0.z, k0.w, k1.x, k1.y, k1.z, k1.w};
            float ff[8];
            *(float4*)&ff[0] = *(const float4*)&s_f[i * 8];
            *(float4*)&ff[4] = *(const float4*)&s_f[i * 8 + 4];
#pragma unroll
            for (int l = 0; l < KR; ++l) {
                float kl = kk[l];
#pragma unroll
                for (int m = 0; m < KR; ++m)
                    acc[m] = fmaf(kl, ff[(m - l) & 7], acc[m]);
            }
        }
        int rt = pp / OCH, o = pp - rt * OCH;
        uint4 u;
        u.x = pack_bf16x2(acc[0], acc[1]);
        u.y = pack_bf16x2(acc[2], acc[3]);
        u.z = pack_bf16x2(acc[4], acc[5]);
        u.w = pack_bf16x2(acc[6], acc[7]);
        *(uint4*)&Hb[(size_t)(bn * RTOT + rt) * ROWLEN + o * 8] = u;
    }
}

// ---------------------------------------------------------------------------
// In-register 64-lane butterfly reduce of 8 floats.
// ---------------------------------------------------------------------------
__device__ __forceinline__ void bfly8(float acc[8]) {
#pragma unroll
    for (int off = 1; off < 64; off <<= 1) {
#pragma unroll
        for (int j = 0; j < 8; ++j) acc[j] += __shfl_xor(acc[j], off);
    }
}

// ---------------------------------------------------------------------------
// k_H0: per-source vehicle-layer H at t=0 (256 threads, startup only).
// ---------------------------------------------------------------------------
__global__ __launch_bounds__(256) void k_H0(const float* __restrict__ inb,
        const float4* __restrict__ KT, unsigned short* __restrict__ Hb) {
    __shared__ __align__(16) float s_f[192];
    int bs = blockIdx.x, tid = threadIdx.x;
    if (tid < 192) s_f[tid] = inb[bs * 192 + tid];
    __syncthreads();
    h_phase<24, 384, 8, 64, 256>(tid, bs, s_f, KT, Hb);
}

// ---------------------------------------------------------------------------
// k_AM (merged close+open, 1024 threads):
//   H2(bf16) agg (butterfly) -> outD -> outputs[t-1] -> p update ->
//   map encoder (1 point/thread) -> gate+enc -> feat -> Hv(bf16).
// ---------------------------------------------------------------------------
__global__ __launch_bounds__(1024) void k_AM(int t,
        float* __restrict__ p, const float* __restrict__ out2buf,
        const unsigned short* __restrict__ H2b, const float* __restrict__ Wd2,
        const float* __restrict__ w4, const int* __restrict__ bin4,
        const float* __restrict__ w_rho1, float* __restrict__ feat,
        const float* __restrict__ WdBack, const float* __restrict__ Kmap,
        const float* __restrict__ map_p, const float* __restrict__ map_feat,
        const float* __restrict__ map_mask,
        const float4* __restrict__ KTv, unsigned short* __restrict__ Hvb,
        float* __restrict__ out) {
    __shared__ float s_w[256];
    __shared__ int   s_row[256];
    __shared__ float s_in[64];
    __shared__ float s_p2[16 * 8];
    __shared__ float s_oD[24];
    __shared__ float s_w2[16];
    __shared__ float s_G16[16 * 96];
    __shared__ float s_G[96];
    __shared__ float s_wred[16];
    __shared__ __align__(16) float s_f2[192];

    int tid = threadIdx.x, bn = blockIdx.x, b = bn >> 6, n = bn & 63;
    int w = tid >> 6, lane = tid & 63;
    float2 pold = *(const float2*)&p[bn * 2];

    // map preload: 1 point per thread (T14 issue-early)
    float2 mp = *(const float2*)&map_p[(b * NM + tid) * 2];
    float  mm = map_mask[b * NM + tid];
    float2 mf = *(const float2*)&map_feat[(b * NM + tid) * 2];

    if (tid < 256) {
        s_w[tid] = w4[bn * 256 + tid];
        s_row[tid] = (b * NV + (tid >> 2)) * RTOT + bin4[bn * 256 + tid];
    }
    if (tid >= 256 && tid < 320) s_in[tid - 256] = out2buf[bn * 64 + (tid - 256)];
    if (tid >= 320 && tid < 336) {
        int r = tid - 320, m = r >> 1, dd = r & 1;
        float ang = TWO_PIF * (float)m / (float)KR;
        float sn, cs; sincosf(ang, &sn, &cs);
        float w0 = w_rho1[0], wq = w_rho1[1];
        s_w2[r] = (dd == 0) ? (w0 * cs - wq * sn) : (w0 * sn + wq * cs);
    }
    for (int i = tid; i < 16 * 96; i += 1024) s_G16[i] = 0.f;
    __syncthreads();

    // ---- H2 aggregation: 1 load/thread + butterfly
    {
        int cgrp = w >> 2, esub = w & 3;          // 4 col-groups x 4 entry-subsets
        int e = esub * 64 + lane;
        float we = s_w[e];
        uint4 u = *(const uint4*)&H2b[(size_t)s_row[e] * 32 + cgrp * 8];
        float2 q0 = unpack_bf16x2(u.x), q1 = unpack_bf16x2(u.y);
        float2 q2 = unpack_bf16x2(u.z), q3 = unpack_bf16x2(u.w);
        float acc[8] = {we * q0.x, we * q0.y, we * q1.x, we * q1.y,
                        we * q2.x, we * q2.y, we * q3.x, we * q3.y};
        bfly8(acc);
        if (lane == 0) {
#pragma unroll
            for (int j = 0; j < 8; ++j) s_p2[w * 8 + j] = acc[j];
        }
    }
    __syncthreads();
    if (tid < 24) {
        int cgrp = tid >> 3, j = tid & 7;
        float tot = s_p2[(cgrp * 4 + 0) * 8 + j] + s_p2[(cgrp * 4 + 1) * 8 + j]
                  + s_p2[(cgrp * 4 + 2) * 8 + j] + s_p2[(cgrp * 4 + 3) * 8 + j];
        int o = tid / KR, m = tid & 7;
#pragma unroll
        for (int i = 0; i < 8; ++i) {
            const float* Wr = Wd2 + (o * 8 + i) * KR;
#pragma unroll
            for (int l = 0; l < KR; ++l)
                tot = fmaf(Wr[l], fmaxf(s_in[i * KR + ((m - l) & 7)], 0.f), tot);
        }
        s_oD[tid] = fmaxf(tot, 0.f);
    }
    __syncthreads();

    // ---- outputs[t-1] + position update (all threads compute delta)
    float dx0 = 0.f, dy0 = 0.f;
#pragma unroll
    for (int m = 0; m < KR; ++m) {
        float v = s_oD[m];
        dx0 = fmaf(v, s_w2[m * 2 + 0], dx0);
        dy0 = fmaf(v, s_w2[m * 2 + 1], dy0);
    }
    if (tid < 6) {
        int c = tid >> 1, dd = tid & 1;
        float acc = 0.f;
#pragma unroll
        for (int m = 0; m < KR; ++m)
            acc = fmaf(s_oD[c * KR + m], s_w2[m * 2 + dd], acc);
        if (c == 0) acc += (dd ? pold.y : pold.x);
        out[(((t - 1) * NB + b) * NV + n) * 6 + tid] = acc;
    }
    float pdx = pold.x + dx0, pdy = pold.y + dy0;
    if (tid == 0) { p[bn * 2 + 0] = pdx; p[bn * 2 + 1] = pdy; }

    // ---- map accumulation: single round
    float lc;
    {
        float valid, win; int bin[4]; float cw[4];
        pair_geom(mp.x - pdx, mp.y - pdy, mm, valid, win, bin, cw);
        lc = valid;
        float ww = valid * win;
        float* myG = &s_G16[w * 96];
        if (ww > 0.f) {
#pragma unroll
            for (int q = 0; q < 4; ++q) {
                float wq_ = ww * cw[q];
                atomicAdd(&myG[bin[q] * 2 + 0], wq_ * mf.x);
                atomicAdd(&myG[bin[q] * 2 + 1], wq_ * mf.y);
            }
        }
    }
#pragma unroll
    for (int off = 1; off < 64; off <<= 1) lc += __shfl_xor(lc, off);
    if (lane == 0) s_wred[w] = lc;
    __syncthreads();
    if (tid < 96) {
        float g = 0.f;
#pragma unroll
        for (int c = 0; c < 16; ++c) g += s_G16[c * 96 + tid];
        s_G[tid] = g;
    }
    __syncthreads();

    // ---- enc (tid<64) + back gate (tid in [128,256))
    if (tid < 64) {
        float cnt = 0.f;
#pragma unroll
        for (int c = 0; c < 16; ++c) cnt += s_wred[c];
        float invc = 1.0f / fmaxf(cnt, 1.0f);
        float acc = 0.f;
#pragma unroll 8
        for (int rt = 0; rt < RTOT; ++rt) {
            float2 k2 = *(const float2*)&Kmap[(rt * 64 + tid) * 2];
            acc = fmaf(k2.x, s_G[rt * 2 + 0], acc);
            acc = fmaf(k2.y, s_G[rt * 2 + 1], acc);
        }
        s_f2[128 + tid] = fmaxf(acc * invc, 0.f);
    }
    if (tid >= 128 && tid < 256) {
        int r = tid - 128, i = r >> 3, m = r & 7;
        float acc = 0.f;
#pragma unroll
        for (int c = 0; c < 3; ++c)
#pragma unroll
            for (int l = 0; l < KR; ++l)
                acc = fmaf(WdBack[(i * 3 + c) * 8 + l], s_oD[c * 8 + ((m - l) & 7)], acc);
        s_f2[r] = feat[bn * 192 + r] * tanhf(acc);
    }
    __syncthreads();
    if (tid < 192) feat[bn * 192 + tid] = s_f2[tid];

    // ---- Hv from s_f2 (single round: tid<384)
    h_phase<24, 384, 8, 64, 1024>(tid, bn, s_f2, KTv, Hvb);
}

// ---------------------------------------------------------------------------
// k_B (1024 threads): pair weights; layer-1 agg (bf16 Hv, butterfly) +
// equilinear -> out1; H1(bf16).
// ---------------------------------------------------------------------------
__global__ __launch_bounds__(1024) void k_B(
        const float* __restrict__ p, const float* __restrict__ car_mask,
        const float* __restrict__ feat, const unsigned short* __restrict__ Hvb,
        const float* __restrict__ WdV,
        float* __restrict__ w4, int* __restrict__ bin4,
        const float4* __restrict__ KT1,
        float* __restrict__ out1, unsigned short* __restrict__ H1b) {
    __shared__ float s_psrc[NV * 2];
    __shared__ float s_w[256];
    __shared__ int   s_row[256];
    __shared__ __align__(16) float s_in[192];
    __shared__ float s_p[16 * 8];
    __shared__ __align__(16) float s_f2[64];
    int tid = threadIdx.x, bn = blockIdx.x, b = bn >> 6, n = bn & 63;
    int w = tid >> 6, lane = tid & 63;
    if (tid < 128) s_psrc[tid] = p[b * 128 + tid];
    if (tid >= 256 && tid < 448) s_in[tid - 256] = feat[bn * 192 + (tid - 256)];
    __syncthreads();
    // pair weights on wave 0
    if (tid < NV) {
        int s = tid;
        float valid, win; int bin[4]; float cw[4];
        pair_geom(s_psrc[s * 2 + 0] - s_psrc[n * 2 + 0],
                  s_psrc[s * 2 + 1] - s_psrc[n * 2 + 1],
                  car_mask[b * NV + s], valid, win, bin, cw);
        float c = valid;
#pragma unroll
        for (int off = 32; off > 0; off >>= 1) c += __shfl_xor(c, off);
        float bw = valid * win / fmaxf(c, 1.0f);
#pragma unroll
        for (int q = 0; q < 4; ++q) {
            float wv = bw * cw[q];
            s_w[s * 4 + q] = wv;
            s_row[s * 4 + q] = (b * NV + s) * RTOT + bin[q];
            w4[bn * 256 + s * 4 + q] = wv;
            bin4[bn * 256 + s * 4 + q] = bin[q];
        }
    }
    __syncthreads();
    // agg64 butterfly: wave w -> cgrp=w>>1, esub=w&1; 2 loads/thread
    {
        int cgrp = w >> 1, esub = w & 1;
        int e0 = esub * 128 + lane, e1 = e0 + 64;
        float we0 = s_w[e0], we1 = s_w[e1];
        uint4 u0 = *(const uint4*)&Hvb[(size_t)s_row[e0] * 64 + cgrp * 8];
        uint4 u1 = *(const uint4*)&Hvb[(size_t)s_row[e1] * 64 + cgrp * 8];
        float acc[8];
        {
            float2 a0 = unpack_bf16x2(u0.x), a1 = unpack_bf16x2(u0.y);
            float2 a2 = unpack_bf16x2(u0.z), a3 = unpack_bf16x2(u0.w);
            float2 b0 = unpack_bf16x2(u1.x), b1 = unpack_bf16x2(u1.y);
            float2 b2 = unpack_bf16x2(u1.z), b3 = unpack_bf16x2(u1.w);
            acc[0] = we0 * a0.x + we1 * b0.x; acc[1] = we0 * a0.y + we1 * b0.y;
            acc[2] = we0 * a1.x + we1 * b1.x; acc[3] = we0 * a1.y + we1 * b1.y;
            acc[4] = we0 * a2.x + we1 * b2.x; acc[5] = we0 * a2.y + we1 * b2.y;
            acc[6] = we0 * a3.x + we1 * b3.x; acc[7] = we0 * a3.y + we1 * b3.y;
        }
        bfly8(acc);
        if (lane == 0) {
#pragma unroll
            for (int j = 0; j < 8; ++j) s_p[w * 8 + j] = acc[j];
        }
    }
    __syncthreads();
    if (tid < 64) {
        int cgrp = tid >> 3, j = tid & 7;
        float tot = s_p[(cgrp * 2 + 0) * 8 + j] + s_p[(cgrp * 2 + 1) * 8 + j];
        int o = tid >> 3, m = tid & 7;
#pragma unroll
        for (int i = 0; i < 24; ++i) {
            const float* Wr = WdV + (o * 24 + i) * KR;
#pragma unroll
            for (int l = 0; l < KR; ++l)
                tot = fmaf(Wr[l], s_in[i * KR + ((m - l) & 7)], tot);
        }
        out1[bn * 64 + tid] = tot;
        s_f2[tid] = fmaxf(tot, 0.f);
    }
    __syncthreads();
    h_phase<8, 384, 8, 64, 1024>(tid, bn, s_f2, KT1, H1b);
}

// ---------------------------------------------------------------------------
// k_C (1024 threads): layer-2 agg (bf16 H1, butterfly) + equilinear +
// residual -> out2; H2(bf16, 32-col rows).
// ---------------------------------------------------------------------------
__global__ __launch_bounds__(1024) void k_C(const float* __restrict__ out1,
        const unsigned short* __restrict__ H1b, const float* __restrict__ Wd1,
        const float* __restrict__ w4, const int* __restrict__ bin4,
        const float4* __restrict__ KT2, float* __restrict__ out2,
        unsigned short* __restrict__ H2b) {
    __shared__ float s_w[256];
    __shared__ int   s_row[256];
    __shared__ float s_in[64];
    __shared__ float s_p[16 * 8];
    __shared__ __align__(16) float s_f2[64];
    int tid = threadIdx.x, bn = blockIdx.x, b = bn >> 6;
    int w = tid >> 6, lane = tid & 63;
    if (tid < 256) {
        s_w[tid] = w4[bn * 256 + tid];
        s_row[tid] = (b * NV + (tid >> 2)) * RTOT + bin4[bn * 256 + tid];
    }
    if (tid >= 256 && tid < 320) s_in[tid - 256] = out1[bn * 64 + (tid - 256)];
    __syncthreads();
    {
        int cgrp = w >> 1, esub = w & 1;
        int e0 = esub * 128 + lane, e1 = e0 + 64;
        float we0 = s_w[e0], we1 = s_w[e1];
        uint4 u0 = *(const uint4*)&H1b[(size_t)s_row[e0] * 64 + cgrp * 8];
        uint4 u1 = *(const uint4*)&H1b[(size_t)s_row[e1] * 64 + cgrp * 8];
        float acc[8];
        {
            float2 a0 = unpack_bf16x2(u0.x), a1 = unpack_bf16x2(u0.y);
            float2 a2 = unpack_bf16x2(u0.z), a3 = unpack_bf16x2(u0.w);
            float2 b0 = unpack_bf16x2(u1.x), b1 = unpack_bf16x2(u1.y);
            float2 b2 = unpack_bf16x2(u1.z), b3 = unpack_bf16x2(u1.w);
            acc[0] = we0 * a0.x + we1 * b0.x; acc[1] = we0 * a0.y + we1 * b0.y;
            acc[2] = we0 * a1.x + we1 * b1.x; acc[3] = we0 * a1.y + we1 * b1.y;
            acc[4] = we0 * a2.x + we1 * b2.x; acc[5] = we0 * a2.y + we1 * b2.y;
            acc[6] = we0 * a3.x + we1 * b3.x; acc[7] = we0 * a3.y + we1 * b3.y;
        }
        bfly8(acc);
        if (lane == 0) {
#pragma unroll
            for (int j = 0; j < 8; ++j) s_p[w * 8 + j] = acc[j];
        }
    }
    __syncthreads();
    if (tid < 64) {
        int cgrp = tid >> 3, j = tid & 7;
        float tot = s_p[(cgrp * 2 + 0) * 8 + j] + s_p[(cgrp * 2 + 1) * 8 + j];
        int o = tid >> 3, m = tid & 7;
#pragma unroll
        for (int i = 0; i < 8; ++i) {
            const float* Wr = Wd1 + (o * 8 + i) * KR;
#pragma unroll
            for (int l = 0; l < KR; ++l)
                tot = fmaf(Wr[l], fmaxf(s_in[i * KR + ((m - l) & 7)], 0.f), tot);
        }
        tot += s_in[tid];
        out2[bn * 64 + tid] = tot;
        s_f2[tid] = fmaxf(tot, 0.f);
    }
    __syncthreads();
    h_phase<8, 144, 3, 32, 1024>(tid, bn, s_f2, KT2, H2b);
}

// ---------------------------------------------------------------------------
// k_fin (1024 threads): agg H2_29 -> outD_29; outputs[29].
// ---------------------------------------------------------------------------
__global__ __launch_bounds__(1024) void k_fin(
        const float* __restrict__ p, const float* __restrict__ out2buf,
        const unsigned short* __restrict__ H2b, const float* __restrict__ Wd2,
        const float* __restrict__ w4, const int* __restrict__ bin4,
        const float* __restrict__ w_rho1, float* __restrict__ out) {
    __shared__ float s_w[256];
    __shared__ int   s_row[256];
    __shared__ float s_in[64];
    __shared__ float s_p2[16 * 8];
    __shared__ float s_oD[24];
    __shared__ float s_w2[16];
    int tid = threadIdx.x, bn = blockIdx.x, b = bn >> 6, n = bn & 63;
    int w = tid >> 6, lane = tid & 63;
    if (tid < 256) {
        s_w[tid] = w4[bn * 256 + tid];
        s_row[tid] = (b * NV + (tid >> 2)) * RTOT + bin4[bn * 256 + tid];
    }
    if (tid >= 256 && tid < 320) s_in[tid - 256] = out2buf[bn * 64 + (tid - 256)];
    if (tid >= 320 && tid < 336) {
        int r = tid - 320, m = r >> 1, dd = r & 1;
        float ang = TWO_PIF * (float)m / (float)KR;
        float sn, cs; sincosf(ang, &sn, &cs);
        float w0 = w_rho1[0], wq = w_rho1[1];
        s_w2[r] = (dd == 0) ? (w0 * cs - wq * sn) : (w0 * sn + wq * cs);
    }
    __syncthreads();
    {
        int cgrp = w >> 2, esub = w & 3;
        int e = esub * 64 + lane;
        float we = s_w[e];
        uint4 u = *(const uint4*)&H2b[(size_t)s_row[e] * 32 + cgrp * 8];
        float2 q0 = unpack_bf16x2(u.x), q1 = unpack_bf16x2(u.y);
        float2 q2 = unpack_bf16x2(u.z), q3 = unpack_bf16x2(u.w);
        float acc[8] = {we * q0.x, we * q0.y, we * q1.x, we * q1.y,
                        we * q2.x, we * q2.y, we * q3.x, we * q3.y};
        bfly8(acc);
        if (lane == 0) {
#pragma unroll
            for (int j = 0; j < 8; ++j) s_p2[w * 8 + j] = acc[j];
        }
    }
    __syncthreads();
    if (tid < 24) {
        int cgrp = tid >> 3, j = tid & 7;
        float tot = s_p2[(cgrp * 4 + 0) * 8 + j] + s_p2[(cgrp * 4 + 1) * 8 + j]
                  + s_p2[(cgrp * 4 + 2) * 8 + j] + s_p2[(cgrp * 4 + 3) * 8 + j];
        int o = tid / KR, m = tid & 7;
#pragma unroll
        for (int i = 0; i < 8; ++i) {
            const float* Wr = Wd2 + (o * 8 + i) * KR;
#pragma unroll
            for (int l = 0; l < KR; ++l)
                tot = fmaf(Wr[l], fmaxf(s_in[i * KR + ((m - l) & 7)], 0.f), tot);
        }
        s_oD[tid] = fmaxf(tot, 0.f);
    }
    __syncthreads();
    if (tid < 6) {
        int c = tid >> 1, dd = tid & 1;
        float acc = 0.f;
#pragma unroll
        for (int m = 0; m < KR; ++m)
            acc = fmaf(s_oD[c * KR + m], s_w2[m * 2 + dd], acc);
        if (c == 0) acc += p[bn * 2 + dd];
        out[((29 * NB + b) * NV + n) * 6 + tid] = acc;
    }
}

// ---------------------------------------------------------------------------
extern "C" void kernel_launch(void* const* d_in, const int* in_sizes, int n_in,
                              void* d_out, int out_size, void* d_ws, size_t ws_size,
                              hipStream_t stream) {
    const float* in_p     = (const float*)d_in[0];
    const float* in_feat  = (const float*)d_in[1];
    const float* map_p    = (const float*)d_in[2];
    const float* map_feat = (const float*)d_in[3];
    const float* car_mask = (const float*)d_in[4];
    const float* map_mask = (const float*)d_in[5];
    const float* Kv       = (const float*)d_in[6];
    const float* WdV      = (const float*)d_in[7];
    const float* K1       = (const float*)d_in[8];
    const float* Wd1      = (const float*)d_in[9];
    const float* K2       = (const float*)d_in[10];
    const float* Wd2      = (const float*)d_in[11];
    const float* WdBack   = (const float*)d_in[12];
    const float* w_rho1   = (const float*)d_in[13];
    const float* Kmap     = (const float*)d_in[14];

    float* ws   = (float*)d_ws;
    float* pbuf  = ws;                       // 1024
    float* feat  = ws + 2048;                // 98304  [512][192]
    float* out1  = ws + 100352;              // 32768
    float* out2  = ws + 133120;              // 32768
    float* w4    = ws + 178176;              // 131072
    int*   bin4  = (int*)(ws + 309248);      // 131072 ints
    float4* KTv  = (float4*)(ws + 440320);   // 73728 floats
    float4* KT1  = (float4*)(ws + 514048);   // 24576 floats
    float4* KT2  = (float4*)(ws + 538624);   // 9216 floats
    unsigned short* Hvb = (unsigned short*)(ws + 547840);   // 512*48*64 bf16
    unsigned short* H1b = (unsigned short*)(ws + 1334272);  // 512*48*64 bf16
    unsigned short* H2b = (unsigned short*)(ws + 2120704);  // 512*48*32 bf16
    float* out   = (float*)d_out;

    hipMemcpyAsync(pbuf, in_p, NB * NV * 2 * sizeof(float),
                   hipMemcpyDeviceToDevice, stream);
    hipMemcpyAsync(feat, in_feat, NB * NV * 24 * KR * sizeof(float),
                   hipMemcpyDeviceToDevice, stream);

    k_trans<<<105, 256, 0, stream>>>(Kv, K1, K2, KTv, KT1, KT2);
    k_H0<<<NB * NV, 256, 0, stream>>>(feat, KTv, Hvb);

    // step 0 decode (p_0, feat_0, Hv_0 ready)
    k_B<<<NB * NV, 1024, 0, stream>>>(pbuf, car_mask, feat, Hvb, WdV, w4, bin4, KT1, out1, H1b);
    k_C<<<NB * NV, 1024, 0, stream>>>(out1, H1b, Wd1, w4, bin4, KT2, out2, H2b);

    for (int t = 1; t < 30; ++t) {
        k_AM<<<NB * NV, 1024, 0, stream>>>(t, pbuf, out2, H2b, Wd2, w4, bin4,
                                           w_rho1, feat, WdBack, Kmap, map_p,
                                           map_feat, map_mask, KTv, Hvb, out);
        k_B<<<NB * NV, 1024, 0, stream>>>(pbuf, car_mask, feat, Hvb, WdV, w4, bin4, KT1, out1, H1b);
        k_C<<<NB * NV, 1024, 0, stream>>>(out1, H1b, Wd1, w4, bin4, KT2, out2, H2b);
    }
    k_fin<<<NB * NV, 1024, 0, stream>>>(pbuf, out2, H2b, Wd2, w4, bin4, w_rho1, out);
}

// Round 16
// 1636.958 us; speedup vs baseline: 1.2342x; 1.2342x over previous
//
#include <hip/hip_runtime.h>
#include <math.h>

#define NB 8
#define NV 64
#define NM 1024
#define NR 3
#define NT 16
#define KR 8
#define RTOT 48                 // NR*NT
#define RADIUSF 40.0f
#define TWO_PIF 6.283185307179586f

// ---------------------------------------------------------------------------
// bf16 pack/unpack (RNE). Unpack exact. Validated R14 (absmax 2e-3).
// ---------------------------------------------------------------------------
__device__ __forceinline__ unsigned int pack_bf16x2(float a, float b) {
    unsigned int ua = __float_as_uint(a), ub = __float_as_uint(b);
    ua = (ua + 0x7FFFu + ((ua >> 16) & 1u)) >> 16;
    ub = (ub + 0x7FFFu + ((ub >> 16) & 1u)) & 0xFFFF0000u;
    return ua | ub;
}
__device__ __forceinline__ float2 unpack_bf16x2(unsigned int u) {
    float2 r;
    r.x = __uint_as_float(u << 16);
    r.y = __uint_as_float(u & 0xFFFF0000u);
    return r;
}

// ---------------------------------------------------------------------------
// Branchless fast atan2 (validated R12-R14).
// ---------------------------------------------------------------------------
__device__ __forceinline__ float fast_atan2(float y, float x) {
    float ax = fabsf(x), ay = fabsf(y);
    float mx = fmaxf(ax, ay), mn = fminf(ax, ay);
    float z = mn / fmaxf(mx, 1e-30f);
    float z2 = z * z;
    float r = fmaf(z2, fmaf(z2, fmaf(z2, fmaf(z2, 0.0208351f, -0.0851330f),
                                     0.1801410f), -0.3302995f), 0.9998660f) * z;
    r = (ay > ax) ? (1.57079637f - r) : r;
    r = (x < 0.f) ? (3.14159274f - r) : r;
    return (y < 0.f) ? -r : r;
}

// ---------------------------------------------------------------------------
// Pair geometry: reference bilinear polar binning.
// ---------------------------------------------------------------------------
__device__ __forceinline__ void pair_geom(float relx, float rely, float mask,
                                          float& valid, float& win,
                                          int bin[4], float cw[4]) {
    float d = sqrtf(relx * relx + rely * rely + 1e-12f);
    valid = (d < RADIUSF) ? mask : 0.0f;
    float q = d * (1.0f / RADIUSF);
    float w1 = fmaxf(1.0f - q * q, 0.0f);
    win = w1 * w1 * w1;
    float u = fminf(fmaxf(q, 0.0f), 1.0f) * (float)(NR - 1);
    float r0f = floorf(u);
    float wr = u - r0f;
    int r0 = (int)r0f;
    int r1 = min(r0 + 1, NR - 1);
    float a = fast_atan2(rely, relx) * (1.0f / TWO_PIF);
    a = a - floorf(a);                  // mod 1 -> [0,1)
    float t = a * (float)NT;
    float t0f = floorf(t);
    float wt = t - t0f;
    int t0 = ((int)t0f) & (NT - 1);
    int t1 = (t0 + 1) & (NT - 1);
    bin[0] = r0 * NT + t0; cw[0] = (1.0f - wr) * (1.0f - wt);
    bin[1] = r0 * NT + t1; cw[1] = (1.0f - wr) * wt;
    bin[2] = r1 * NT + t0; cw[2] = wr * (1.0f - wt);
    bin[3] = r1 * NT + t1; cw[3] = wr * wt;
}

// ---------------------------------------------------------------------------
// k_pairs0: step-0 pair weights from initial positions. One wave per (b,n).
// ---------------------------------------------------------------------------
__global__ __launch_bounds__(64) void k_pairs0(const float* __restrict__ p,
                                               const float* __restrict__ car_mask,
                                               float* __restrict__ w4,
                                               int* __restrict__ bin4) {
    int b = blockIdx.x >> 6, n = blockIdx.x & 63;
    int s = threadIdx.x;
    float dx = p[(b * NV + n) * 2 + 0], dy = p[(b * NV + n) * 2 + 1];
    float relx = p[(b * NV + s) * 2 + 0] - dx;
    float rely = p[(b * NV + s) * 2 + 1] - dy;
    float valid, win; int bin[4]; float cw[4];
    pair_geom(relx, rely, car_mask[b * NV + s], valid, win, bin, cw);
    float c = valid;
#pragma unroll
    for (int off = 32; off > 0; off >>= 1) c += __shfl_xor(c, off);
    float bw = valid * win / fmaxf(c, 1.0f);
    int base = (blockIdx.x * NV + s) * 4;
#pragma unroll
    for (int q = 0; q < 4; ++q) { w4[base + q] = bw * cw[q]; bin4[base + q] = bin[q]; }
}

// ---------------------------------------------------------------------------
// One-time K transpose: KT[chunk j][pair p].
// ---------------------------------------------------------------------------
__global__ __launch_bounds__(256) void k_trans(
        const float* __restrict__ Kv, const float* __restrict__ K1g,
        const float* __restrict__ K2g, float4* __restrict__ KTv,
        float4* __restrict__ KT1, float4* __restrict__ KT2) {
    int idx = blockIdx.x * 256 + threadIdx.x;
    if (idx < 48 * 384) {
        int j = idx / 384, p = idx % 384;
        KTv[idx] = *(const float4*)(Kv + p * 192 + j * 4);
    } else if (idx < 48 * 384 + 16 * 384) {
        int r = idx - 48 * 384;
        int j = r / 384, p = r % 384;
        KT1[r] = *(const float4*)(K1g + p * 64 + j * 4);
    } else if (idx < 48 * 384 + 16 * 384 + 16 * 144) {
        int r = idx - (48 * 384 + 16 * 384);
        int j = r / 144, p = r % 144;
        KT2[r] = *(const float4*)(K2g + p * 64 + j * 4);
    }
}

// ---------------------------------------------------------------------------
// h_phase: circular conv of LDS feature row with KT -> bf16 H rows.
// ---------------------------------------------------------------------------
template<int ICH, int NPAIR, int OCH, int ROWLEN>
__device__ __forceinline__ void h_phase(int tid, int bn, const float* s_f,
        const float4* __restrict__ KT, unsigned short* __restrict__ Hb) {
    for (int pp = tid; pp < NPAIR; pp += 256) {
        float acc[KR];
#pragma unroll
        for (int m = 0; m < KR; ++m) acc[m] = 0.f;
#pragma unroll 8
        for (int i = 0; i < ICH; ++i) {
            float4 k0 = KT[(2 * i) * NPAIR + pp];
            float4 k1 = KT[(2 * i + 1) * NPAIR + pp];
            float kk[8] = {k0.x, k0.y, k0.z, k0.w, k1.x, k1.y, k1.z, k1.w};
            float ff[8];
            *(float4*)&ff[0] = *(const float4*)&s_f[i * 8];
            *(float4*)&ff[4] = *(const float4*)&s_f[i * 8 + 4];
#pragma unroll
            for (int l = 0; l < KR; ++l) {
                float kl = kk[l];
#pragma unroll
                for (int m = 0; m < KR; ++m)
                    acc[m] = fmaf(kl, ff[(m - l) & 7], acc[m]);
            }
        }
        int rt = pp / OCH, o = pp - rt * OCH;
        uint4 u;
        u.x = pack_bf16x2(acc[0], acc[1]);
        u.y = pack_bf16x2(acc[2], acc[3]);
        u.z = pack_bf16x2(acc[4], acc[5]);
        u.w = pack_bf16x2(acc[6], acc[7]);
        *(uint4*)&Hb[(size_t)(bn * RTOT + rt) * ROWLEN + o * 8] = u;
    }
}

// ---------------------------------------------------------------------------
// k_H0: per-source vehicle-layer H at t=0.
// ---------------------------------------------------------------------------
__global__ __launch_bounds__(256) void k_H0(const float* __restrict__ inb,
        const float4* __restrict__ KT, unsigned short* __restrict__ Hb) {
    __shared__ __align__(16) float s_f[192];
    int bs = blockIdx.x, tid = threadIdx.x;
    if (tid < 192) s_f[tid] = inb[bs * 192 + tid];
    __syncthreads();
    h_phase<24, 384, 8, 64>(tid, bs, s_f, KT, Hb);
}

// ---------------------------------------------------------------------------
// bf16 aggregation over 64-col rows (Hv/H1). s_part must be [32*64].
// ---------------------------------------------------------------------------
__device__ __forceinline__ void agg64_bf16(int tid, const float* s_w,
        const int* s_row, const unsigned short* __restrict__ Hb,
        float* s_part) {
    int w = tid >> 6, lane = tid & 63;
    int g = lane >> 3, c = lane & 7;
    float acc[8];
#pragma unroll
    for (int m = 0; m < 8; ++m) acc[m] = 0.f;
#pragma unroll
    for (int r = 0; r < 8; ++r) {
        int idx = w * 64 + r * 8 + g;
        float we = s_w[idx];
        uint4 u = *(const uint4*)&Hb[(size_t)s_row[idx] * 64 + c * 8];
        float2 q0 = unpack_bf16x2(u.x), q1 = unpack_bf16x2(u.y);
        float2 q2 = unpack_bf16x2(u.z), q3 = unpack_bf16x2(u.w);
        acc[0] = fmaf(we, q0.x, acc[0]); acc[1] = fmaf(we, q0.y, acc[1]);
        acc[2] = fmaf(we, q1.x, acc[2]); acc[3] = fmaf(we, q1.y, acc[3]);
        acc[4] = fmaf(we, q2.x, acc[4]); acc[5] = fmaf(we, q2.y, acc[5]);
        acc[6] = fmaf(we, q3.x, acc[6]); acc[7] = fmaf(we, q3.y, acc[7]);
    }
    float* pp = &s_part[(w * 8 + g) * 64 + c * 8];
#pragma unroll
    for (int m = 0; m < 8; ++m) pp[m] = acc[m];
}

// ---------------------------------------------------------------------------
// bf16 aggregation over 32-col rows (H2; cols 24-31 pad, never reduced).
// s_part must be [64*32].
// ---------------------------------------------------------------------------
__device__ __forceinline__ void agg32_bf16(int tid, const float* s_w,
        const int* s_row, const unsigned short* __restrict__ Hb,
        float* s_part) {
    int w = tid >> 6, lane = tid & 63;
    int g = lane >> 2, c = lane & 3;
    float acc[8];
#pragma unroll
    for (int m = 0; m < 8; ++m) acc[m] = 0.f;
#pragma unroll
    for (int r = 0; r < 4; ++r) {
        int idx = w * 64 + r * 16 + g;
        float we = s_w[idx];
        uint4 u = *(const uint4*)&Hb[(size_t)s_row[idx] * 32 + c * 8];
        float2 q0 = unpack_bf16x2(u.x), q1 = unpack_bf16x2(u.y);
        float2 q2 = unpack_bf16x2(u.z), q3 = unpack_bf16x2(u.w);
        acc[0] = fmaf(we, q0.x, acc[0]); acc[1] = fmaf(we, q0.y, acc[1]);
        acc[2] = fmaf(we, q1.x, acc[2]); acc[3] = fmaf(we, q1.y, acc[3]);
        acc[4] = fmaf(we, q2.x, acc[4]); acc[5] = fmaf(we, q2.y, acc[5]);
        acc[6] = fmaf(we, q3.x, acc[6]); acc[7] = fmaf(we, q3.y, acc[7]);
    }
    float* pp = &s_part[(w * 16 + g) * 32 + c * 8];
#pragma unroll
    for (int m = 0; m < 8; ++m) pp[m] = acc[m];
}

// ---------------------------------------------------------------------------
// k_A1: close step t-1. H2(bf16) agg -> outD -> oDbuf; outputs[t-1]; p update.
// ---------------------------------------------------------------------------
__global__ __launch_bounds__(256) void k_A1(int t,
        float* __restrict__ p, const float* __restrict__ out2buf,
        const unsigned short* __restrict__ H2b, const float* __restrict__ Wd2,
        const float* __restrict__ w4, const int* __restrict__ bin4,
        const float* __restrict__ w_rho1,
        float* __restrict__ oDbuf, float* __restrict__ out) {
    __shared__ float s_w[256];
    __shared__ int   s_row[256];
    __shared__ float s_in[64];
    __shared__ __align__(16) float s_part[64 * 32];
    __shared__ float s_oD[24];
    __shared__ float s_w2[16];
    int tid = threadIdx.x, bn = blockIdx.x, b = bn >> 6, n = bn & 63;
    float2 pold = *(const float2*)&p[bn * 2];

    s_w[tid] = w4[bn * 256 + tid];
    s_row[tid] = (b * NV + (tid >> 2)) * RTOT + bin4[bn * 256 + tid];
    if (tid < 64) s_in[tid] = out2buf[bn * 64 + tid];
    if (tid >= 224 && tid < 240) {
        int r = tid - 224, m = r >> 1, dd = r & 1;
        float ang = TWO_PIF * (float)m / (float)KR;
        float sn, cs; sincosf(ang, &sn, &cs);
        float w0 = w_rho1[0], wq = w_rho1[1];
        s_w2[r] = (dd == 0) ? (w0 * cs - wq * sn) : (w0 * sn + wq * cs);
    }
    __syncthreads();

    agg32_bf16(tid, s_w, s_row, H2b, s_part);
    __syncthreads();
    if (tid < 24) {
        float tot = 0.f;
#pragma unroll
        for (int k = 0; k < 64; ++k) tot += s_part[k * 32 + tid];
        int o = tid / KR, m = tid & 7;
#pragma unroll
        for (int i = 0; i < 8; ++i) {
            const float* Wr = Wd2 + (o * 8 + i) * KR;
#pragma unroll
            for (int l = 0; l < KR; ++l)
                tot = fmaf(Wr[l], fmaxf(s_in[i * KR + ((m - l) & 7)], 0.f), tot);
        }
        float v = fmaxf(tot, 0.f);
        s_oD[tid] = v;
        oDbuf[bn * 24 + tid] = v;
    }
    __syncthreads();

    float dx0 = 0.f, dy0 = 0.f;
#pragma unroll
    for (int m = 0; m < KR; ++m) {
        float v = s_oD[m];
        dx0 = fmaf(v, s_w2[m * 2 + 0], dx0);
        dy0 = fmaf(v, s_w2[m * 2 + 1], dy0);
    }
    if (tid < 6) {
        int c = tid >> 1, dd = tid & 1;
        float acc = 0.f;
#pragma unroll
        for (int m = 0; m < KR; ++m)
            acc = fmaf(s_oD[c * KR + m], s_w2[m * 2 + dd], acc);
        if (c == 0) acc += (dd ? pold.y : pold.x);
        out[(((t - 1) * NB + b) * NV + n) * 6 + tid] = acc;
    }
    if (tid == 0) {
        p[bn * 2 + 0] = pold.x + dx0;
        p[bn * 2 + 1] = pold.y + dy0;
    }
}

// ---------------------------------------------------------------------------
// k_A2: open step t. Pair weights (wave 0, concurrent with other waves' map
// work) + map encoder + back gate -> feat; Hv (bf16).
// ---------------------------------------------------------------------------
__global__ __launch_bounds__(256) void k_A2(
        const float* __restrict__ p, const float* __restrict__ oDbuf,
        float* __restrict__ feat, const float* __restrict__ WdBack,
        const float* __restrict__ Kmap, const float* __restrict__ map_p,
        const float* __restrict__ map_feat, const float* __restrict__ map_mask,
        const float* __restrict__ car_mask,
        float* __restrict__ w4, int* __restrict__ bin4,
        const float4* __restrict__ KTv, unsigned short* __restrict__ Hvb) {
    __shared__ float s_psrc[NV * 2];
    __shared__ float s_oD[24];
    __shared__ float s_G4[4 * 96];
    __shared__ float s_G[96];
    __shared__ float s_wred[4];
    __shared__ __align__(16) float s_f2[192];
    int tid = threadIdx.x, bn = blockIdx.x, b = bn >> 6, n = bn & 63;

    float2 pn = *(const float2*)&p[bn * 2];
    float pdx = pn.x, pdy = pn.y;

    // T14: preload all map data
    float2 mp[4], mf[4]; float mm[4];
#pragma unroll
    for (int j = 0; j < 4; ++j) {
        int s = tid + j * 256;
        mp[j] = *(const float2*)&map_p[(b * NM + s) * 2];
        mm[j] = map_mask[b * NM + s];
        mf[j] = *(const float2*)&map_feat[(b * NM + s) * 2];
    }
    if (tid < 24) s_oD[tid] = oDbuf[bn * 24 + tid];
    if (tid >= 128) s_psrc[tid - 128] = p[b * 128 + (tid - 128)];
    if (tid < 96) { s_G4[tid] = 0.f; s_G4[96 + tid] = 0.f; s_G4[192 + tid] = 0.f; s_G4[288 + tid] = 0.f; }
    __syncthreads();

    // ---- pair weights (wave 0) — overlaps with waves 1-3 starting map work
    if (tid < NV) {
        int s = tid;
        float valid, win; int bin[4]; float cw[4];
        pair_geom(s_psrc[s * 2 + 0] - pdx, s_psrc[s * 2 + 1] - pdy,
                  car_mask[b * NV + s], valid, win, bin, cw);
        float c = valid;
#pragma unroll
        for (int off = 32; off > 0; off >>= 1) c += __shfl_xor(c, off);
        float bw = valid * win / fmaxf(c, 1.0f);
        int base = (bn * NV + s) * 4;
#pragma unroll
        for (int q = 0; q < 4; ++q) { w4[base + q] = bw * cw[q]; bin4[base + q] = bin[q]; }
    }

    // ---- map accumulation from preloaded registers
    float lc = 0.f;
    float* myG = &s_G4[(tid >> 6) * 96];
#pragma unroll
    for (int j = 0; j < 4; ++j) {
        float valid, win; int bin[4]; float cw[4];
        pair_geom(mp[j].x - pdx, mp[j].y - pdy, mm[j], valid, win, bin, cw);
        lc += valid;
        float ww = valid * win;
        if (ww > 0.f) {
#pragma unroll
            for (int q = 0; q < 4; ++q) {
                float w = ww * cw[q];
                atomicAdd(&myG[bin[q] * 2 + 0], w * mf[j].x);
                atomicAdd(&myG[bin[q] * 2 + 1], w * mf[j].y);
            }
        }
    }
#pragma unroll
    for (int off = 32; off > 0; off >>= 1) lc += __shfl_xor(lc, off);
    if ((tid & 63) == 0) s_wred[tid >> 6] = lc;
    __syncthreads();
    if (tid < 96) s_G[tid] = s_G4[tid] + s_G4[96 + tid] + s_G4[192 + tid] + s_G4[288 + tid];
    __syncthreads();
    float invc = 1.0f / fmaxf(s_wred[0] + s_wred[1] + s_wred[2] + s_wred[3], 1.0f);

    if (tid < 64) {
        float acc = 0.f;
#pragma unroll 8
        for (int rt = 0; rt < RTOT; ++rt) {
            float2 k2 = *(const float2*)&Kmap[(rt * 64 + tid) * 2];
            acc = fmaf(k2.x, s_G[rt * 2 + 0], acc);
            acc = fmaf(k2.y, s_G[rt * 2 + 1], acc);
        }
        s_f2[128 + tid] = fmaxf(acc * invc, 0.f);
    }
    if (tid >= 128) {
        int r = tid - 128, i = r >> 3, m = r & 7;
        float acc = 0.f;
#pragma unroll
        for (int c = 0; c < 3; ++c)
#pragma unroll
            for (int l = 0; l < KR; ++l)
                acc = fmaf(WdBack[(i * 3 + c) * 8 + l], s_oD[c * 8 + ((m - l) & 7)], acc);
        s_f2[r] = feat[bn * 192 + r] * tanhf(acc);
    }
    __syncthreads();
    if (tid < 192) feat[bn * 192 + tid] = s_f2[tid];

    h_phase<24, 384, 8, 64>(tid, bn, s_f2, KTv, Hvb);
}

// ---------------------------------------------------------------------------
// k_B: layer-1 aggregation (bf16 Hv) + equilinear -> out1; H1 (bf16).
// Pair weights already in w4/bin4 (k_A2 / k_pairs0).
// ---------------------------------------------------------------------------
__global__ __launch_bounds__(256) void k_B(
        const float* __restrict__ feat, const unsigned short* __restrict__ Hvb,
        const float* __restrict__ WdV,
        const float* __restrict__ w4, const int* __restrict__ bin4,
        const float4* __restrict__ KT1,
        float* __restrict__ out1, unsigned short* __restrict__ H1b) {
    __shared__ float s_w[256];
    __shared__ int   s_row[256];
    __shared__ __align__(16) float s_in[192];
    __shared__ __align__(16) float s_part[32 * 64];
    __shared__ __align__(16) float s_f2[64];
    int tid = threadIdx.x, bn = blockIdx.x, b = bn >> 6;
    s_w[tid] = w4[bn * 256 + tid];
    s_row[tid] = (b * NV + (tid >> 2)) * RTOT + bin4[bn * 256 + tid];
    if (tid < 192) s_in[tid] = feat[bn * 192 + tid];
    __syncthreads();
    agg64_bf16(tid, s_w, s_row, Hvb, s_part);
    __syncthreads();
    if (tid < 64) {
        float tot = 0.f;
#pragma unroll
        for (int k = 0; k < 32; ++k) tot += s_part[k * 64 + tid];
        int o = tid >> 3, m = tid & 7;
#pragma unroll
        for (int i = 0; i < 24; ++i) {
            const float* Wr = WdV + (o * 24 + i) * KR;
#pragma unroll
            for (int l = 0; l < KR; ++l)
                tot = fmaf(Wr[l], s_in[i * KR + ((m - l) & 7)], tot);
        }
        out1[bn * 64 + tid] = tot;
        s_f2[tid] = fmaxf(tot, 0.f);
    }
    __syncthreads();
    h_phase<8, 384, 8, 64>(tid, bn, s_f2, KT1, H1b);
}

// ---------------------------------------------------------------------------
// k_C: layer-2 aggregation (bf16 H1) + equilinear + residual -> out2;
// H2 (bf16, 32-col rows) from relu(out2).
// ---------------------------------------------------------------------------
__global__ __launch_bounds__(256) void k_C(const float* __restrict__ out1,
        const unsigned short* __restrict__ H1b, const float* __restrict__ Wd1,
        const float* __restrict__ w4, const int* __restrict__ bin4,
        const float4* __restrict__ KT2, float* __restrict__ out2,
        unsigned short* __restrict__ H2b) {
    __shared__ float s_w[256];
    __shared__ int   s_row[256];
    __shared__ float s_in[64];
    __shared__ __align__(16) float s_part[32 * 64];
    __shared__ __align__(16) float s_f2[64];
    int tid = threadIdx.x, bn = blockIdx.x, b = bn >> 6;
    s_w[tid] = w4[bn * 256 + tid];
    s_row[tid] = (b * NV + (tid >> 2)) * RTOT + bin4[bn * 256 + tid];
    if (tid < 64) s_in[tid] = out1[bn * 64 + tid];
    __syncthreads();
    agg64_bf16(tid, s_w, s_row, H1b, s_part);
    __syncthreads();
    if (tid < 64) {
        float tot = 0.f;
#pragma unroll
        for (int k = 0; k < 32; ++k) tot += s_part[k * 64 + tid];
        int o = tid >> 3, m = tid & 7;
#pragma unroll
        for (int i = 0; i < 8; ++i) {
            const float* Wr = Wd1 + (o * 8 + i) * KR;
#pragma unroll
            for (int l = 0; l < KR; ++l)
                tot = fmaf(Wr[l], fmaxf(s_in[i * KR + ((m - l) & 7)], 0.f), tot);
        }
        tot += s_in[tid];
        out2[bn * 64 + tid] = tot;
        s_f2[tid] = fmaxf(tot, 0.f);
    }
    __syncthreads();
    h_phase<8, 144, 3, 32>(tid, bn, s_f2, KT2, H2b);
}

// ---------------------------------------------------------------------------
// k_fin: aggregate H2_29 (bf16) -> outD_29; outputs[29] = reg2rho1 + p_29.
// ---------------------------------------------------------------------------
__global__ __launch_bounds__(256) void k_fin(
        const float* __restrict__ p, const float* __restrict__ out2buf,
        const unsigned short* __restrict__ H2b, const float* __restrict__ Wd2,
        const float* __restrict__ w4, const int* __restrict__ bin4,
        const float* __restrict__ w_rho1, float* __restrict__ out) {
    __shared__ float s_w[256];
    __shared__ int   s_row[256];
    __shared__ float s_in[64];
    __shared__ __align__(16) float s_part[64 * 32];
    __shared__ float s_oD[24];
    __shared__ float s_w2[16];
    int tid = threadIdx.x, bn = blockIdx.x, b = bn >> 6, n = bn & 63;
    s_w[tid] = w4[bn * 256 + tid];
    s_row[tid] = (b * NV + (tid >> 2)) * RTOT + bin4[bn * 256 + tid];
    if (tid < 64) s_in[tid] = out2buf[bn * 64 + tid];
    if (tid >= 224 && tid < 240) {
        int r = tid - 224, m = r >> 1, dd = r & 1;
        float ang = TWO_PIF * (float)m / (float)KR;
        float sn, cs; sincosf(ang, &sn, &cs);
        float w0 = w_rho1[0], wq = w_rho1[1];
        s_w2[r] = (dd == 0) ? (w0 * cs - wq * sn) : (w0 * sn + wq * cs);
    }
    __syncthreads();
    agg32_bf16(tid, s_w, s_row, H2b, s_part);
    __syncthreads();
    if (tid < 24) {
        float tot = 0.f;
#pragma unroll
        for (int k = 0; k < 64; ++k) tot += s_part[k * 32 + tid];
        int o = tid / KR, m = tid & 7;
#pragma unroll
        for (int i = 0; i < 8; ++i) {
            const float* Wr = Wd2 + (o * 8 + i) * KR;
#pragma unroll
            for (int l = 0; l < KR; ++l)
                tot = fmaf(Wr[l], fmaxf(s_in[i * KR + ((m - l) & 7)], 0.f), tot);
        }
        s_oD[tid] = fmaxf(tot, 0.f);
    }
    __syncthreads();
    if (tid < 6) {
        int c = tid >> 1, dd = tid & 1;
        float acc = 0.f;
#pragma unroll
        for (int m = 0; m < KR; ++m)
            acc = fmaf(s_oD[c * KR + m], s_w2[m * 2 + dd], acc);
        if (c == 0) acc += p[bn * 2 + dd];
        out[((29 * NB + b) * NV + n) * 6 + tid] = acc;
    }
}

// ---------------------------------------------------------------------------
extern "C" void kernel_launch(void* const* d_in, const int* in_sizes, int n_in,
                              void* d_out, int out_size, void* d_ws, size_t ws_size,
                              hipStream_t stream) {
    const float* in_p     = (const float*)d_in[0];
    const float* in_feat  = (const float*)d_in[1];
    const float* map_p    = (const float*)d_in[2];
    const float* map_feat = (const float*)d_in[3];
    const float* car_mask = (const float*)d_in[4];
    const float* map_mask = (const float*)d_in[5];
    const float* Kv       = (const float*)d_in[6];
    const float* WdV      = (const float*)d_in[7];
    const float* K1       = (const float*)d_in[8];
    const float* Wd1      = (const float*)d_in[9];
    const float* K2       = (const float*)d_in[10];
    const float* Wd2      = (const float*)d_in[11];
    const float* WdBack   = (const float*)d_in[12];
    const float* w_rho1   = (const float*)d_in[13];
    const float* Kmap     = (const float*)d_in[14];

    float* ws   = (float*)d_ws;
    float* pbuf  = ws;                       // 1024
    float* feat  = ws + 2048;                // 98304  [512][192]
    float* out1  = ws + 100352;              // 32768
    float* out2  = ws + 133120;              // 32768
    float* w4    = ws + 178176;              // 131072
    int*   bin4  = (int*)(ws + 309248);      // 131072 ints
    float4* KTv  = (float4*)(ws + 440320);   // 73728 floats
    float4* KT1  = (float4*)(ws + 514048);   // 24576 floats
    float4* KT2  = (float4*)(ws + 538624);   // 9216 floats
    unsigned short* Hvb = (unsigned short*)(ws + 547840);   // 512*48*64 bf16
    unsigned short* H1b = (unsigned short*)(ws + 1334272);  // 512*48*64 bf16
    unsigned short* H2b = (unsigned short*)(ws + 2120704);  // 512*48*32 bf16
    float* oDbuf = ws + 2513920;             // 12288
    float* out   = (float*)d_out;

    hipMemcpyAsync(pbuf, in_p, NB * NV * 2 * sizeof(float),
                   hipMemcpyDeviceToDevice, stream);
    hipMemcpyAsync(feat, in_feat, NB * NV * 24 * KR * sizeof(float),
                   hipMemcpyDeviceToDevice, stream);

    k_trans<<<105, 256, 0, stream>>>(Kv, K1, K2, KTv, KT1, KT2);
    k_H0<<<NB * NV, 256, 0, stream>>>(feat, KTv, Hvb);
    k_pairs0<<<NB * NV, 64, 0, stream>>>(pbuf, car_mask, w4, bin4);

    // step 0 decode (p_0, feat_0, Hv_0, w4/bin4 ready)
    k_B<<<NB * NV, 256, 0, stream>>>(feat, Hvb, WdV, w4, bin4, KT1, out1, H1b);
    k_C<<<NB * NV, 256, 0, stream>>>(out1, H1b, Wd1, w4, bin4, KT2, out2, H2b);

    for (int t = 1; t < 30; ++t) {
        k_A1<<<NB * NV, 256, 0, stream>>>(t, pbuf, out2, H2b, Wd2, w4, bin4,
                                          w_rho1, oDbuf, out);
        k_A2<<<NB * NV, 256, 0, stream>>>(pbuf, oDbuf, feat, WdBack, Kmap,
                                          map_p, map_feat, map_mask, car_mask,
                                          w4, bin4, KTv, Hvb);
        k_B<<<NB * NV, 256, 0, stream>>>(feat, Hvb, WdV, w4, bin4, KT1, out1, H1b);
        k_C<<<NB * NV, 256, 0, stream>>>(out1, H1b, Wd1, w4, bin4, KT2, out2, H2b);
    }
    k_fin<<<NB * NV, 256, 0, stream>>>(pbuf, out2, H2b, Wd2, w4, bin4, w_rho1, out);
}